// Round 1
// baseline (247.407 us; speedup 1.0000x reference)
//
#include <hip/hip_runtime.h>
#include <hip/hip_bf16.h>

// Problem constants (fixed by the reference setup)
#define BB 8
#define SS 4096
#define DD 1024
#define HH 16
#define HD 64
#define NR 32
#define NROWS (BB * SS * HH)      // 524288 head-vectors of length 64

// ---------------------------------------------------------------------------
// Kernel A: build the combined 64x64 matrix C = R0*R1*...*R31 * r_matrix.
// Trick: apply rotations as ROW ops on r_matrix in reverse order (W <- Rk*W),
// so no 64x64 GEMM is needed. One block, trivial runtime.
// ---------------------------------------------------------------------------
__global__ __launch_bounds__(256) void build_C_kernel(
    const float* __restrict__ thetas,
    const float* __restrict__ r_pairs,
    const float* __restrict__ theta_scale,
    const float* __restrict__ r_matrix,
    float* __restrict__ C_out)
{
    __shared__ float W[64 * 68];     // 64x64, row stride 68 (bank spread)
    __shared__ int   ii[NR], jj[NR];
    __shared__ float cc[NR], ss[NR];

    const int t = threadIdx.x;

    // Load r_matrix into W
#pragma unroll
    for (int it = 0; it < 16; ++it) {
        int idx = t + 256 * it;                  // 0..4095
        W[(idx >> 6) * 68 + (idx & 63)] = r_matrix[idx];
    }
    // Precompute rotation params
    if (t < NR) {
        ii[t] = (int)r_pairs[2 * t];             // truncation == astype(int32) for >=0
        jj[t] = (int)r_pairs[2 * t + 1];
        float th = thetas[t] * theta_scale[0];
        cc[t] = cosf(th);
        ss[t] = sinf(th);
    }
    __syncthreads();

    // Apply W <- Rk * W for k = 31..0 (row ops; thread t owns column t)
    if (t < 64) {
        for (int k = NR - 1; k >= 0; --k) {
            int i = ii[k], j = jj[k];
            float c = cc[k], s = ss[k];
            float xi = W[i * 68 + t];
            float xj = W[j * 68 + t];
            if (i == j) {
                W[i * 68 + t] = c * xi;          // matches reference i==j semantics
            } else {
                W[i * 68 + t] = c * xi - s * xj; // new row_i
                W[j * 68 + t] = s * xi + c * xj; // new row_j
            }
        }
    }
    __syncthreads();

    // Store C (row-major, stride 64) to workspace
#pragma unroll
    for (int it = 0; it < 16; ++it) {
        int idx = t + 256 * it;
        C_out[idx] = W[(idx >> 6) * 68 + (idx & 63)];
    }
}

// ---------------------------------------------------------------------------
// Kernel B: per-row  y = x_row @ C  (64x64 matvec) fused with RoPE epilogue.
// Block = 256 threads, 128 rows/block. x-tile transposed in LDS for b128
// fragment reads; C row-major in LDS. Thread tile = 4 rows x 8 y-cols.
// ---------------------------------------------------------------------------
#define RPB 128
#define XT_STRIDE 132

__global__ __launch_bounds__(256) void rope_main_kernel(
    const float* __restrict__ x,
    const float* __restrict__ C,
    const float* __restrict__ inv_freq,
    float* __restrict__ out)
{
    __shared__ float Cs[64 * 64];            // 16 KB
    __shared__ float xT[64 * XT_STRIDE];     // 33 KB  (transposed x-tile)

    const int t = threadIdx.x;
    const size_t tile = (size_t)blockIdx.x * (RPB * HD);   // float offset

    // Stage C: 4096 floats, float4-coalesced
    {
        const float4* C4  = (const float4*)C;
        float4*       Cs4 = (float4*)Cs;
#pragma unroll
        for (int it = 0; it < 4; ++it)
            Cs4[t + 256 * it] = C4[t + 256 * it];
    }
    // Stage x-tile transposed: global float4 (coalesced) -> 4 scalar LDS writes
    {
        const float4* x4 = (const float4*)(x + tile);
#pragma unroll
        for (int it = 0; it < 8; ++it) {
            int f = t + 256 * it;            // 0..2047 (float4 index in tile)
            float4 v = x4[f];
            int row = f >> 4;                // f / 16  (16 float4 per row)
            int k4  = (f & 15) << 2;         // k base
            xT[(k4 + 0) * XT_STRIDE + row] = v.x;
            xT[(k4 + 1) * XT_STRIDE + row] = v.y;
            xT[(k4 + 2) * XT_STRIDE + row] = v.z;
            xT[(k4 + 3) * XT_STRIDE + row] = v.w;
        }
    }
    __syncthreads();

    const int jq = t & 7;            // 8 col-groups
    const int rg = t >> 3;           // 32 row-groups
    const int j0 = jq << 3;          // 8 consecutive y-cols
    const int r0 = rg << 2;          // 4 consecutive rows

    float acc[4][8];
#pragma unroll
    for (int u = 0; u < 4; ++u)
#pragma unroll
        for (int v = 0; v < 8; ++v) acc[u][v] = 0.0f;

#pragma unroll 4
    for (int k = 0; k < 64; ++k) {
        const float4 av  = *(const float4*)&xT[k * XT_STRIDE + r0];
        const float4 bv0 = *(const float4*)&Cs[(k << 6) + j0];
        const float4 bv1 = *(const float4*)&Cs[(k << 6) + j0 + 4];
        const float a[4] = {av.x, av.y, av.z, av.w};
        const float b[8] = {bv0.x, bv0.y, bv0.z, bv0.w, bv1.x, bv1.y, bv1.z, bv1.w};
#pragma unroll
        for (int u = 0; u < 4; ++u)
#pragma unroll
            for (int v = 0; v < 8; ++v)
                acc[u][v] = fmaf(a[u], b[v], acc[u][v]);
    }

    // Epilogue: RoPE. All 4 rows of this thread share one sequence position
    // (rows are h-fastest, H=16, r0 is 4-aligned => same s).
    const size_t grow0 = (size_t)blockIdx.x * RPB + r0;
    const int   s_pos  = (int)((grow0 >> 4) & (SS - 1));   // (row/H) % S
    const float pos    = (float)s_pos;

    const int rbase = j0 >> 1;                              // 4 pairs: rbase..rbase+3
    const float4 invf = *(const float4*)&inv_freq[rbase];   // rbase % 4 == 0
    float cs[4], sn[4];
    __sincosf(pos * invf.x, &sn[0], &cs[0]);
    __sincosf(pos * invf.y, &sn[1], &cs[1]);
    __sincosf(pos * invf.z, &sn[2], &cs[2]);
    __sincosf(pos * invf.w, &sn[3], &cs[3]);

#pragma unroll
    for (int u = 0; u < 4; ++u) {
        float* orow = out + tile + (size_t)(r0 + u) * HD;
        float4 o1, o2;
        o1.x = acc[u][0] * cs[0] - acc[u][1] * sn[0];
        o1.y = acc[u][2] * cs[1] - acc[u][3] * sn[1];
        o1.z = acc[u][4] * cs[2] - acc[u][5] * sn[2];
        o1.w = acc[u][6] * cs[3] - acc[u][7] * sn[3];
        o2.x = acc[u][0] * sn[0] + acc[u][1] * cs[0];
        o2.y = acc[u][2] * sn[1] + acc[u][3] * cs[1];
        o2.z = acc[u][4] * sn[2] + acc[u][5] * cs[2];
        o2.w = acc[u][6] * sn[3] + acc[u][7] * cs[3];
        *(float4*)&orow[rbase]      = o1;
        *(float4*)&orow[32 + rbase] = o2;
    }
}

// ---------------------------------------------------------------------------
extern "C" void kernel_launch(void* const* d_in, const int* in_sizes, int n_in,
                              void* d_out, int out_size, void* d_ws, size_t ws_size,
                              hipStream_t stream)
{
    const float* x           = (const float*)d_in[0];
    const float* thetas      = (const float*)d_in[1];
    const float* r_pairs     = (const float*)d_in[2];
    const float* theta_scale = (const float*)d_in[3];
    // d_in[4] = n_rots_scale (unused by the reference)
    const float* r_matrix    = (const float*)d_in[5];
    const float* inv_freq    = (const float*)d_in[6];
    float* out = (float*)d_out;
    float* Cws = (float*)d_ws;               // 64*64 floats = 16 KB scratch

    build_C_kernel<<<1, 256, 0, stream>>>(thetas, r_pairs, theta_scale, r_matrix, Cws);

    const int nblocks = NROWS / RPB;         // 4096
    rope_main_kernel<<<nblocks, 256, 0, stream>>>(x, Cws, inv_freq, out);
}